// Round 1
// baseline (2993.290 us; speedup 1.0000x reference)
//
#include <hip/hip_runtime.h>

#define NN 100000
#define NE 1600000

// ---------------------------------------------------------------------------
// edge_index dtype detection: if data is int64 (little-endian, values < 2^31),
// every odd 32-bit word of the first 2*NE words is zero. If int32, those words
// are random edge indices (some nonzero with overwhelming probability).
__global__ void k_detect(const unsigned int* w, int* flag) {
    int i = blockIdx.x * blockDim.x + threadIdx.x;
    int stride = gridDim.x * blockDim.x;
    for (int idx = i; idx < NE; idx += stride) {
        if (w[2 * idx + 1] != 0u) { *flag = 1; return; }
    }
}

__global__ void k_convert(const void* ei, const int* flag, int* src, int* dst) {
    int e = blockIdx.x * blockDim.x + threadIdx.x;
    if (e >= NE) return;
    if (*flag == 0) {  // int64 layout
        const long long* p = (const long long*)ei;
        src[e] = (int)p[e];
        dst[e] = (int)p[NE + e];
    } else {           // int32 layout
        const int* p = (const int*)ei;
        src[e] = p[e];
        dst[e] = p[NE + e];
    }
}

__global__ void k_degree(const int* __restrict__ dst, int* __restrict__ deg) {
    int e = blockIdx.x * blockDim.x + threadIdx.x;
    if (e < NE) atomicAdd(&deg[dst[e]], 1);
}

__global__ void k_dinv(const int* __restrict__ deg, float* __restrict__ dinv) {
    int n = blockIdx.x * blockDim.x + threadIdx.x;
    if (n < NN) dinv[n] = rsqrtf((float)(deg[n] + 1));  // +1 self-loop
}

// ---------------------------------------------------------------------------
// Layer 1 transform: t[n][j] = dinv[n] * (x[n][0]*W1[0][j] + x[n][1]*W1[1][j])
__global__ void k_transform1(const float* __restrict__ x, const float* __restrict__ W1,
                             const float* __restrict__ dinv, float* __restrict__ t) {
    int tid = blockIdx.x * blockDim.x + threadIdx.x;
    if (tid >= NN * 64) return;
    int n = tid >> 6, j = tid & 63;
    float v = x[2 * n] * W1[j] + x[2 * n + 1] * W1[64 + j];
    t[tid] = dinv[n] * v;
}

// 64x64 GEMM transform: t[n][:] = dinv[n] * (h[n][:] @ W)
__global__ __launch_bounds__(256) void k_gemm64(const float* __restrict__ h,
                                                const float* __restrict__ W,
                                                const float* __restrict__ dinv,
                                                float* __restrict__ t) {
    __shared__ float Ws[64 * 64];
    __shared__ float hs[4][64];
    int tx = threadIdx.x & 63, ty = threadIdx.x >> 6;
    for (int i = threadIdx.x; i < 64 * 64; i += 256) Ws[i] = W[i];
    __syncthreads();
    int base = blockIdx.x * 64;
    for (int it = 0; it < 16; ++it) {
        int n = base + it * 4 + ty;
        if (n < NN) hs[ty][tx] = h[(size_t)n * 64 + tx];
        __syncthreads();
        if (n < NN) {
            float acc = 0.f;
#pragma unroll
            for (int k = 0; k < 64; ++k) acc += hs[ty][k] * Ws[k * 64 + tx];
            t[(size_t)n * 64 + tx] = dinv[n] * acc;
        }
        __syncthreads();
    }
}

// 64->1 transform: t3[n] = dinv[n] * dot(h[n][:], W3)
__global__ void k_transform3(const float* __restrict__ h, const float* __restrict__ W3,
                             const float* __restrict__ dinv, float* __restrict__ t3) {
    int tid = blockIdx.x * blockDim.x + threadIdx.x;
    if (tid >= NN * 64) return;
    int n = tid >> 6, k = tid & 63;
    float v = h[(size_t)n * 64 + k] * W3[k];
#pragma unroll
    for (int off = 32; off > 0; off >>= 1) v += __shfl_down(v, off, 64);
    if (k == 0) t3[n] = dinv[n] * v;
}

// ---------------------------------------------------------------------------
// Edge scatter: acc[dst][:] += t[src][:]   (16 threads/edge, float4 each)
__global__ void k_scatter(const int* __restrict__ src, const int* __restrict__ dst,
                          const float* __restrict__ t, float* __restrict__ acc) {
    int tid = blockIdx.x * blockDim.x + threadIdx.x;
    int e = tid >> 4;
    if (e >= NE) return;
    int f = (tid & 15) << 2;
    int s = src[e], d = dst[e];
    const float4 v = *(const float4*)&t[(size_t)s * 64 + f];
    float* a = &acc[(size_t)d * 64 + f];
    atomicAdd(a + 0, v.x);
    atomicAdd(a + 1, v.y);
    atomicAdd(a + 2, v.z);
    atomicAdd(a + 3, v.w);
}

__global__ void k_scatter3(const int* __restrict__ src, const int* __restrict__ dst,
                           const float* __restrict__ t3, float* __restrict__ acc3) {
    int e = blockIdx.x * blockDim.x + threadIdx.x;
    if (e < NE) atomicAdd(&acc3[dst[e]], t3[src[e]]);
}

// ---------------------------------------------------------------------------
// Finalize: h[n][j] = act( dinv[n]*(acc[n][j] + t[n][j]) + b[j] )
__global__ void k_finalize(const float* __restrict__ acc, const float* __restrict__ t,
                           const float* __restrict__ dinv, const float* __restrict__ b,
                           float* __restrict__ h, int relu) {
    int tid = blockIdx.x * blockDim.x + threadIdx.x;
    if (tid >= NN * 64) return;
    int n = tid >> 6, j = tid & 63;
    float v = dinv[n] * (acc[tid] + t[tid]) + b[j];
    if (relu) v = fmaxf(v, 0.f);
    h[tid] = v;
}

__global__ void k_finalize3(const float* __restrict__ acc3, const float* __restrict__ t3,
                            const float* __restrict__ dinv, const float* __restrict__ b3,
                            float* __restrict__ out) {
    int n = blockIdx.x * blockDim.x + threadIdx.x;
    if (n < NN) out[n] = dinv[n] * (acc3[n] + t3[n]) + b3[0];
}

// ---------------------------------------------------------------------------
extern "C" void kernel_launch(void* const* d_in, const int* in_sizes, int n_in,
                              void* d_out, int out_size, void* d_ws, size_t ws_size,
                              hipStream_t stream) {
    const float* x  = (const float*)d_in[0];
    const void*  ei = d_in[1];
    const float* W1 = (const float*)d_in[2];
    const float* b1 = (const float*)d_in[3];
    const float* W2 = (const float*)d_in[4];
    const float* b2 = (const float*)d_in[5];
    const float* W3 = (const float*)d_in[6];
    const float* b3 = (const float*)d_in[7];
    float* out = (float*)d_out;

    char* ws = (char*)d_ws;
    size_t off = 0;
    auto take = [&](size_t bytes) -> char* {
        char* p = ws + off;
        off = (off + bytes + 255) & ~(size_t)255;
        return p;
    };
    float* dinv = (float*)take((size_t)NN * 4);
    int*   deg  = (int*)take((size_t)NN * 4);
    int*   flag = (int*)take(4);
    int*   src  = (int*)take((size_t)NE * 4);
    int*   dst  = (int*)take((size_t)NE * 4);
    float* tb   = (float*)take((size_t)NN * 64 * 4);
    float* ab   = (float*)take((size_t)NN * 64 * 4);
    float* hb   = (float*)take((size_t)NN * 64 * 4);
    float* t3   = (float*)take((size_t)NN * 4);
    float* a3   = (float*)take((size_t)NN * 4);

    // --- setup: edge dtype detect/convert, degrees, dinv ---
    hipMemsetAsync(flag, 0, 4, stream);
    hipMemsetAsync(deg, 0, (size_t)NN * 4, stream);
    k_detect<<<1024, 256, 0, stream>>>((const unsigned int*)ei, flag);
    k_convert<<<(NE + 255) / 256, 256, 0, stream>>>(ei, flag, src, dst);
    k_degree<<<(NE + 255) / 256, 256, 0, stream>>>(dst, deg);
    k_dinv<<<(NN + 255) / 256, 256, 0, stream>>>(deg, dinv);

    const int nblk_nf = (NN * 64 + 255) / 256;     // node*feature grids
    const int nblk_sc = (NE * 16 + 255) / 256;     // scatter grids

    // --- layer 1 ---
    hipMemsetAsync(ab, 0, (size_t)NN * 64 * 4, stream);
    k_transform1<<<nblk_nf, 256, 0, stream>>>(x, W1, dinv, tb);
    k_scatter<<<nblk_sc, 256, 0, stream>>>(src, dst, tb, ab);
    k_finalize<<<nblk_nf, 256, 0, stream>>>(ab, tb, dinv, b1, hb, 1);

    // --- layer 2 ---
    hipMemsetAsync(ab, 0, (size_t)NN * 64 * 4, stream);
    k_gemm64<<<(NN + 63) / 64, 256, 0, stream>>>(hb, W2, dinv, tb);
    k_scatter<<<nblk_sc, 256, 0, stream>>>(src, dst, tb, ab);
    k_finalize<<<nblk_nf, 256, 0, stream>>>(ab, tb, dinv, b2, hb, 1);

    // --- layer 3 ---
    hipMemsetAsync(a3, 0, (size_t)NN * 4, stream);
    k_transform3<<<nblk_nf, 256, 0, stream>>>(hb, W3, dinv, t3);
    k_scatter3<<<(NE + 255) / 256, 256, 0, stream>>>(src, dst, t3, a3);
    k_finalize3<<<(NN + 255) / 256, 256, 0, stream>>>(a3, t3, dinv, b3, out);
}

// Round 2
// 447.343 us; speedup vs baseline: 6.6913x; 6.6913x over previous
//
#include <hip/hip_runtime.h>

#define NN 100000
#define NE 1600000
#define NBLK_SCAN ((NN + 1023) / 1024)   // 98 blocks of 1024 elems

// ---------------------------------------------------------------------------
// edge_index dtype detection: if data is int64 (little-endian, values < 2^31),
// every odd 32-bit word of the first 2*NE words is zero.
__global__ void k_detect(const unsigned int* w, int* flag) {
    int i = blockIdx.x * blockDim.x + threadIdx.x;
    int stride = gridDim.x * blockDim.x;
    for (int idx = i; idx < NE; idx += stride) {
        if (w[2 * idx + 1] != 0u) { *flag = 1; return; }
    }
}

__global__ void k_convert(const void* ei, const int* flag, int* src, int* dst) {
    int e = blockIdx.x * blockDim.x + threadIdx.x;
    if (e >= NE) return;
    if (*flag == 0) {  // int64 layout
        const long long* p = (const long long*)ei;
        src[e] = (int)p[e];
        dst[e] = (int)p[NE + e];
    } else {           // int32 layout
        const int* p = (const int*)ei;
        src[e] = p[e];
        dst[e] = p[NE + e];
    }
}

__global__ void k_degree(const int* __restrict__ dst, int* __restrict__ deg) {
    int e = blockIdx.x * blockDim.x + threadIdx.x;
    if (e < NE) atomicAdd(&deg[dst[e]], 1);
}

__global__ void k_dinv(const int* __restrict__ deg, float* __restrict__ dinv) {
    int n = blockIdx.x * blockDim.x + threadIdx.x;
    if (n < NN) dinv[n] = rsqrtf((float)(deg[n] + 1));  // +1 self-loop
}

// ---------------------------------------------------------------------------
// Exclusive scan of deg -> rowptr (3 kernels)
__global__ __launch_bounds__(256) void k_scan1(const int* __restrict__ deg,
                                               int* __restrict__ ex,
                                               int* __restrict__ bsum) {
    __shared__ int lds[256];
    int b = blockIdx.x, t = threadIdx.x;
    int base = b * 1024 + t * 4;
    int v[4];
#pragma unroll
    for (int k = 0; k < 4; ++k) { int i = base + k; v[k] = (i < NN) ? deg[i] : 0; }
    int s = v[0] + v[1] + v[2] + v[3];
    lds[t] = s;
    __syncthreads();
    for (int off = 1; off < 256; off <<= 1) {
        int tmp = (t >= off) ? lds[t - off] : 0;
        __syncthreads();
        lds[t] += tmp;
        __syncthreads();
    }
    int run = lds[t] - s;  // exclusive offset of this thread within block
#pragma unroll
    for (int k = 0; k < 4; ++k) {
        int i = base + k;
        if (i < NN) ex[i] = run;
        run += v[k];
    }
    if (t == 255) bsum[b] = lds[255];
}

__global__ __launch_bounds__(128) void k_scan2(int* bsum) {
    __shared__ int lds[128];
    int t = threadIdx.x;
    int v = (t < NBLK_SCAN) ? bsum[t] : 0;
    lds[t] = v;
    __syncthreads();
    for (int off = 1; off < 128; off <<= 1) {
        int tmp = (t >= off) ? lds[t - off] : 0;
        __syncthreads();
        lds[t] += tmp;
        __syncthreads();
    }
    if (t < NBLK_SCAN) bsum[t] = lds[t] - v;  // exclusive
}

__global__ void k_scan3(const int* __restrict__ ex, const int* __restrict__ bsum,
                        int* __restrict__ rowptr) {
    int i = blockIdx.x * blockDim.x + threadIdx.x;
    if (i < NN) rowptr[i] = ex[i] + bsum[i >> 10];
    if (i == 0) rowptr[NN] = NE;
}

// Fill CSR: cursor[] starts as a copy of rowptr[0..NN-1]
__global__ void k_fill(const int* __restrict__ src, const int* __restrict__ dst,
                       int* __restrict__ cursor, int* __restrict__ ssrc) {
    int e = blockIdx.x * blockDim.x + threadIdx.x;
    if (e >= NE) return;
    int d = dst[e];
    int pos = atomicAdd(&cursor[d], 1);
    ssrc[pos] = src[e];
}

// ---------------------------------------------------------------------------
// Layer 1 transform: t[n][j] = dinv[n] * (x[n][0]*W1[0][j] + x[n][1]*W1[1][j])
__global__ void k_transform1(const float* __restrict__ x, const float* __restrict__ W1,
                             const float* __restrict__ dinv, float* __restrict__ t) {
    int tid = blockIdx.x * blockDim.x + threadIdx.x;
    if (tid >= NN * 64) return;
    int n = tid >> 6, j = tid & 63;
    float v = x[2 * n] * W1[j] + x[2 * n + 1] * W1[64 + j];
    t[tid] = dinv[n] * v;
}

// 64x64 GEMM transform: t[n][:] = dinv[n] * (h[n][:] @ W)
__global__ __launch_bounds__(256) void k_gemm64(const float* __restrict__ h,
                                                const float* __restrict__ W,
                                                const float* __restrict__ dinv,
                                                float* __restrict__ t) {
    __shared__ float Ws[64 * 64];
    __shared__ float hs[4][64];
    int tx = threadIdx.x & 63, ty = threadIdx.x >> 6;
    for (int i = threadIdx.x; i < 64 * 64; i += 256) Ws[i] = W[i];
    __syncthreads();
    int base = blockIdx.x * 64;
    for (int it = 0; it < 16; ++it) {
        int n = base + it * 4 + ty;
        if (n < NN) hs[ty][tx] = h[(size_t)n * 64 + tx];
        __syncthreads();
        if (n < NN) {
            float acc = 0.f;
#pragma unroll
            for (int k = 0; k < 64; ++k) acc += hs[ty][k] * Ws[k * 64 + tx];
            t[(size_t)n * 64 + tx] = dinv[n] * acc;
        }
        __syncthreads();
    }
}

// 64->1 transform: t3[n] = dinv[n] * dot(h[n][:], W3)
__global__ void k_transform3(const float* __restrict__ h, const float* __restrict__ W3,
                             const float* __restrict__ dinv, float* __restrict__ t3) {
    int tid = blockIdx.x * blockDim.x + threadIdx.x;
    if (tid >= NN * 64) return;
    int n = tid >> 6, k = tid & 63;
    float v = h[(size_t)n * 64 + k] * W3[k];
#pragma unroll
    for (int off = 32; off > 0; off >>= 1) v += __shfl_down(v, off, 64);
    if (k == 0) t3[n] = dinv[n] * v;
}

// ---------------------------------------------------------------------------
// Pull aggregation, fused finalize: one 64-lane wave per node.
// h[n][j] = act( dinv[n]*(t[n][j] + sum_{e in CSR row n} t[src_e][j]) + b[j] )
__global__ __launch_bounds__(256) void k_aggregate(const int* __restrict__ rowptr,
                                                   const int* __restrict__ ssrc,
                                                   const float* __restrict__ t,
                                                   const float* __restrict__ dinv,
                                                   const float* __restrict__ b,
                                                   float* __restrict__ hout, int relu) {
    int node = blockIdx.x * 4 + (threadIdx.x >> 6);
    if (node >= NN) return;
    int lane = threadIdx.x & 63;
    int start = rowptr[node], end = rowptr[node + 1];
    float acc = t[(size_t)node * 64 + lane];  // self loop
    int i = start;
    for (; i + 4 <= end; i += 4) {
        int s0 = ssrc[i], s1 = ssrc[i + 1], s2 = ssrc[i + 2], s3 = ssrc[i + 3];
        float a0 = t[(size_t)s0 * 64 + lane];
        float a1 = t[(size_t)s1 * 64 + lane];
        float a2 = t[(size_t)s2 * 64 + lane];
        float a3 = t[(size_t)s3 * 64 + lane];
        acc += a0 + a1 + a2 + a3;
    }
    for (; i < end; ++i) acc += t[(size_t)ssrc[i] * 64 + lane];
    float v = dinv[node] * acc + b[lane];
    if (relu) v = fmaxf(v, 0.f);
    hout[(size_t)node * 64 + lane] = v;
}

// Scalar variant for the 1-wide last layer: one thread per node.
__global__ void k_aggregate3(const int* __restrict__ rowptr, const int* __restrict__ ssrc,
                             const float* __restrict__ t3, const float* __restrict__ dinv,
                             const float* __restrict__ b3, float* __restrict__ out) {
    int n = blockIdx.x * blockDim.x + threadIdx.x;
    if (n >= NN) return;
    int s = rowptr[n], e = rowptr[n + 1];
    float acc = t3[n];
    int i = s;
    for (; i + 4 <= e; i += 4)
        acc += t3[ssrc[i]] + t3[ssrc[i + 1]] + t3[ssrc[i + 2]] + t3[ssrc[i + 3]];
    for (; i < e; ++i) acc += t3[ssrc[i]];
    out[n] = dinv[n] * acc + b3[0];
}

// ---------------------------------------------------------------------------
extern "C" void kernel_launch(void* const* d_in, const int* in_sizes, int n_in,
                              void* d_out, int out_size, void* d_ws, size_t ws_size,
                              hipStream_t stream) {
    const float* x  = (const float*)d_in[0];
    const void*  ei = d_in[1];
    const float* W1 = (const float*)d_in[2];
    const float* b1 = (const float*)d_in[3];
    const float* W2 = (const float*)d_in[4];
    const float* b2 = (const float*)d_in[5];
    const float* W3 = (const float*)d_in[6];
    const float* b3 = (const float*)d_in[7];
    float* out = (float*)d_out;

    char* ws = (char*)d_ws;
    size_t off = 0;
    auto take = [&](size_t bytes) -> char* {
        char* p = ws + off;
        off = (off + bytes + 255) & ~(size_t)255;
        return p;
    };
    float* dinv   = (float*)take((size_t)NN * 4);
    int*   deg    = (int*)take((size_t)NN * 4);
    int*   flag   = (int*)take(4);
    int*   src    = (int*)take((size_t)NE * 4);
    int*   dst    = (int*)take((size_t)NE * 4);
    int*   ex     = (int*)take((size_t)NN * 4);
    int*   bsum   = (int*)take(128 * 4);
    int*   rowptr = (int*)take((size_t)(NN + 1) * 4);
    int*   cursor = (int*)take((size_t)NN * 4);
    int*   ssrc   = (int*)take((size_t)NE * 4);
    float* tb     = (float*)take((size_t)NN * 64 * 4);
    float* hb     = (float*)take((size_t)NN * 64 * 4);
    float* t3     = (float*)take((size_t)NN * 4);

    // --- setup: edge dtype detect/convert, degrees, dinv ---
    hipMemsetAsync(flag, 0, 4, stream);
    hipMemsetAsync(deg, 0, (size_t)NN * 4, stream);
    k_detect<<<1024, 256, 0, stream>>>((const unsigned int*)ei, flag);
    k_convert<<<(NE + 255) / 256, 256, 0, stream>>>(ei, flag, src, dst);
    k_degree<<<(NE + 255) / 256, 256, 0, stream>>>(dst, deg);
    k_dinv<<<(NN + 255) / 256, 256, 0, stream>>>(deg, dinv);

    // --- CSR build: scan degrees -> rowptr; fill sorted src list ---
    k_scan1<<<NBLK_SCAN, 256, 0, stream>>>(deg, ex, bsum);
    k_scan2<<<1, 128, 0, stream>>>(bsum);
    k_scan3<<<(NN + 255) / 256, 256, 0, stream>>>(ex, bsum, rowptr);
    hipMemcpyAsync(cursor, rowptr, (size_t)NN * 4, hipMemcpyDeviceToDevice, stream);
    k_fill<<<(NE + 255) / 256, 256, 0, stream>>>(src, dst, cursor, ssrc);

    const int nblk_nf  = (NN * 64 + 255) / 256;  // node*feature grids
    const int nblk_agg = (NN + 3) / 4;           // 4 waves (nodes) per block

    // --- layer 1 ---
    k_transform1<<<nblk_nf, 256, 0, stream>>>(x, W1, dinv, tb);
    k_aggregate<<<nblk_agg, 256, 0, stream>>>(rowptr, ssrc, tb, dinv, b1, hb, 1);

    // --- layer 2 ---
    k_gemm64<<<(NN + 63) / 64, 256, 0, stream>>>(hb, W2, dinv, tb);
    k_aggregate<<<nblk_agg, 256, 0, stream>>>(rowptr, ssrc, tb, dinv, b2, hb, 1);

    // --- layer 3 ---
    k_transform3<<<nblk_nf, 256, 0, stream>>>(hb, W3, dinv, t3);
    k_aggregate3<<<(NN + 255) / 256, 256, 0, stream>>>(rowptr, ssrc, t3, dinv, b3, out);
}